// Round 3
// baseline (10624.755 us; speedup 1.0000x reference)
//
#include <hip/hip_runtime.h>
#include <hip/hip_fp16.h>
#include <cmath>

typedef _Float16 f16;
typedef _Float16 half8 __attribute__((ext_vector_type(8)));
typedef float f32x4 __attribute__((ext_vector_type(4)));

#define P_WG   75          // workgroups per direction
#define NKT    30          // K tiles of 32: 10 x-part (K=320 pad of 300) + 20 h-part (K=640 pad of 600)
#define GRID_MAIN (2*P_WG) // 150

#define X16_ELEMS  (64u*512u*320u)            // 10,485,760 f16 per plane
#define BPK_ELEMS  (2u*75u*2u*2u*30u*64u*8u)  // 9,216,000 f16 (hi+lo)
#define BPK_HALF   (BPK_ELEMS/2u)             // 4,608,000 (one term plane)
#define HBUF_F16   (2u*2u*2u*64u*640u)        // dirs*bufs*planes*rows*cols = 655,360 f16
#define HBUF_WORDS (HBUF_F16/2u)              // 327,680 u32

// ---------------- prep: rebuild all workspace state every launch ----------------
__global__ void lstm_prep(const float* __restrict__ x,
                          const float* __restrict__ Wf, const float* __restrict__ Uf,
                          const float* __restrict__ Wb, const float* __restrict__ Ub,
                          const int* __restrict__ len,
                          f16* __restrict__ x16h, f16* __restrict__ x16l,
                          f16* __restrict__ Bpk,
                          unsigned* __restrict__ hbw, unsigned* __restrict__ ctr,
                          int* __restrict__ maxT, float* __restrict__ outp)
{
    const unsigned total = X16_ELEMS + BPK_HALF + HBUF_WORDS + 4u;
    for (unsigned e = blockIdx.x * blockDim.x + threadIdx.x; e < total;
         e += gridDim.x * blockDim.x) {
        if (e < X16_ELEMS) {
            unsigned k = e % 320u, r = e / 320u;   // r = b*512 + t
            float v = (k < 300u) ? x[r * 300u + k] : 0.0f;
            f16 hi = (f16)v;
            x16h[e] = hi;
            x16l[e] = (f16)((v - (float)hi) * 2048.0f);
        } else if (e < X16_ELEMS + BPK_HALF) {
            unsigned i = e - X16_ELEMS;
            // layout: [dir][p][term][nt][kt][lane][8]; this thread fills term=0 and term=1
            unsigned j    = i & 7u,  r1 = i >> 3;
            unsigned lane = r1 & 63u, r2 = r1 >> 6;
            unsigned kt   = r2 % 30u, r3 = r2 / 30u;
            unsigned nt   = r3 & 1u,  r4 = r3 >> 1;
            unsigned p    = r4 % 75u, dw = r4 / 75u;
            unsigned k = kt * 32u + (lane >> 4) * 8u + j;     // B[k][n], k-octet per quad
            unsigned n = nt * 16u + (lane & 15u);             // n = gate*8 + jj
            unsigned c = (n >> 3) * 600u + p * 8u + (n & 7u); // source column in [0,2400)
            float v = 0.0f;
            if (k < 300u)                    v = (dw ? Wb : Wf)[k * 2400u + c];
            else if (k >= 320u && k < 920u)  v = (dw ? Ub : Uf)[(k - 320u) * 2400u + c];
            f16 hi = (f16)v;
            unsigned base = (((((dw * 75u + p) * 2u + 0u) * 2u + nt) * 30u + kt) * 64u + lane) * 8u + j;
            Bpk[base]          = hi;
            Bpk[base + 30720u] = (f16)((v - (float)hi) * 2048.0f); // lo pre-scaled by 2^11
        } else if (e < X16_ELEMS + BPK_HALF + HBUF_WORDS) {
            hbw[e - X16_ELEMS - BPK_HALF] = 0u;   // zero all h ping-pong planes, both dirs
        } else {
            unsigned q = e - (X16_ELEMS + BPK_HALF + HBUF_WORDS);
            if (q == 0u) ctr[0] = 0u;
            else if (q == 1u) ctr[32] = 0u;
            else if (q == 2u) {
                int m = 1;
                for (int b = 0; b < 64; ++b) { int L = len[b]; m = (L > m) ? L : m; }
                *maxT = m;
            } else {
                // diagnostic sentinel: lstm_main always overwrites out[0]; if a
                // future bench fails with absmax~1000, lstm_main did not launch.
                outp[0] = 1000.0f;
            }
        }
    }
}

// ---------------- main persistent recurrent kernel ----------------
__global__ __launch_bounds__(256, 1)
void lstm_main(const f16* __restrict__ x16h, const f16* __restrict__ x16l,
               const f16* __restrict__ Bpk,
               f16* __restrict__ hbuf, unsigned* ctr, const int* __restrict__ maxT,
               const int* __restrict__ len,
               const float* __restrict__ bfv, const float* __restrict__ bbv,
               float* __restrict__ out)
{
    __shared__ f32x4 obox[4][4][2][64];   // [src_wave][mt][nt][lane] : 32 KB merge buffer

    const int tid  = threadIdx.x;
    const int wave = tid >> 6, lane = tid & 63;
    const int quad = lane >> 4, l15 = lane & 15;
    const int dir  = blockIdx.x & 1, p = blockIdx.x >> 1;
    const int pc   = p * 8;

    // ---- persistent B fragments in VGPRs: this wave owns kt = wave + 4*s ----
    half8 Bf[8][2][2];
#pragma unroll
    for (int s = 0; s < 8; ++s) {
        int kt = wave + s * 4;
        if (kt < NKT) {
#pragma unroll
            for (int nt = 0; nt < 2; ++nt)
#pragma unroll
                for (int tm = 0; tm < 2; ++tm)
                    Bf[s][nt][tm] = *(const half8*)(Bpk +
                        (((((dir * 75 + p) * 2 + tm) * 2 + nt) * 30 + kt) * 64 + lane) * 8);
        }
    }
    const float* bias = dir ? bbv : bfv;
    const float bz0 = bias[((l15 >> 3)    ) * 600 + pc + (l15 & 7)];  // gates i|f tile
    const float bz1 = bias[((l15 >> 3) + 2) * 600 + pc + (l15 & 7)];  // gates g|o tile

    int Lm[4], Lr[4];
#pragma unroll
    for (int mt = 0; mt < 4; ++mt) Lm[mt] = len[mt * 16 + l15];        // A-load rows
#pragma unroll
    for (int r = 0; r < 4; ++r)   Lr[r]  = len[wave * 16 + quad * 4 + r]; // epilogue rows

    f16* hb0 = hbuf + dir * (2 * 2 * 64 * 640);     // [buf][plane][row][col]
    unsigned* myctr = ctr + dir * 32;
    float cst[4] = {0, 0, 0, 0}, sum[4] = {0, 0, 0, 0};
    const int T = *maxT;

    for (int t = 0; t < T; ++t) {
        const f16* hcur = hb0 + (t & 1) * (2 * 64 * 640);
        f16*       hnxt = hb0 + ((t + 1) & 1) * (2 * 64 * 640);

        f32x4 accH[4][2], accM[4][2];
#pragma unroll
        for (int mt = 0; mt < 4; ++mt)
#pragma unroll
            for (int nt = 0; nt < 2; ++nt) {
                accH[mt][nt] = f32x4{0.f, 0.f, 0.f, 0.f};
                accM[mt][nt] = f32x4{0.f, 0.f, 0.f, 0.f};
            }

        // ---- x-part (kt<10): no dependence on h, overlaps flag wait ----
#pragma unroll
        for (int s = 0; s < 8; ++s) {
            int kt = wave + s * 4;
            if (kt < 10) {
#pragma unroll
                for (int mt = 0; mt < 4; ++mt) {
                    int row = mt * 16 + l15;
                    int tix = t;
                    if (dir) tix = (t < Lm[mt]) ? (Lm[mt] - 1 - t) : t;   // reverse_sequence
                    unsigned base = ((unsigned)row * 512u + (unsigned)tix) * 320u + kt * 32 + quad * 8;
                    half8 Ah = *(const half8*)(x16h + base);
                    half8 Al = *(const half8*)(x16l + base);
#pragma unroll
                    for (int nt = 0; nt < 2; ++nt) {
                        accH[mt][nt] = __builtin_amdgcn_mfma_f32_16x16x32_f16(Ah, Bf[s][nt][0], accH[mt][nt], 0, 0, 0);
                        accM[mt][nt] = __builtin_amdgcn_mfma_f32_16x16x32_f16(Ah, Bf[s][nt][1], accM[mt][nt], 0, 0, 0);
                        accM[mt][nt] = __builtin_amdgcn_mfma_f32_16x16x32_f16(Al, Bf[s][nt][0], accM[mt][nt], 0, 0, 0);
                    }
                }
            }
        }

        // ---- wait for h_t from all 75 producers of this direction ----
        if (t > 0) {
            const unsigned tgt = (unsigned)(P_WG * t);
            while (__hip_atomic_load(myctr, __ATOMIC_RELAXED, __HIP_MEMORY_SCOPE_AGENT) < tgt)
                __builtin_amdgcn_s_sleep(2);
            __builtin_amdgcn_fence(__ATOMIC_ACQUIRE, "agent");  // inv L1/L2 -> fresh h via cached loads
        }

        // ---- h-part (10<=kt<30) ----
#pragma unroll
        for (int s = 0; s < 8; ++s) {
            int kt = wave + s * 4;
            if (kt >= 10 && kt < NKT) {
#pragma unroll
                for (int mt = 0; mt < 4; ++mt) {
                    int row = mt * 16 + l15;
                    unsigned base = (unsigned)row * 640u + (kt * 32 - 320) + quad * 8;
                    half8 Ah = *(const half8*)(hcur + base);
                    half8 Al = *(const half8*)(hcur + 64 * 640 + base);
#pragma unroll
                    for (int nt = 0; nt < 2; ++nt) {
                        accH[mt][nt] = __builtin_amdgcn_mfma_f32_16x16x32_f16(Ah, Bf[s][nt][0], accH[mt][nt], 0, 0, 0);
                        accM[mt][nt] = __builtin_amdgcn_mfma_f32_16x16x32_f16(Ah, Bf[s][nt][1], accM[mt][nt], 0, 0, 0);
                        accM[mt][nt] = __builtin_amdgcn_mfma_f32_16x16x32_f16(Al, Bf[s][nt][0], accM[mt][nt], 0, 0, 0);
                    }
                }
            }
        }

        // ---- all-to-all K-merge through LDS ----
        __syncthreads();
#pragma unroll
        for (int mt = 0; mt < 4; ++mt)
#pragma unroll
            for (int nt = 0; nt < 2; ++nt)
                obox[wave][mt][nt][lane] = accH[mt][nt] + accM[mt][nt] * (1.0f / 2048.0f);
        __syncthreads();
        f32x4 z0 = obox[0][wave][0][lane] + obox[1][wave][0][lane]
                 + obox[2][wave][0][lane] + obox[3][wave][0][lane];
        f32x4 z1 = obox[0][wave][1][lane] + obox[1][wave][1][lane]
                 + obox[2][wave][1][lane] + obox[3][wave][1][lane];
        z0 += bz0;
        z1 += bz1;

        // ---- epilogue: this wave owns batch rows wave*16 .. wave*16+15 ----
#pragma unroll
        for (int r = 0; r < 4; ++r) {
            float zi = z0[r], zg = z1[r];
            float zf = __shfl_xor(z0[r], 8, 64);  // f gate lives 8 lanes over
            float zo = __shfl_xor(z1[r], 8, 64);
            if (l15 < 8) {
                float ig = 1.0f / (1.0f + __expf(-zi));
                float fg = 1.0f / (1.0f + __expf(-zf));
                float gg = tanhf(zg);
                float og = 1.0f / (1.0f + __expf(-zo));
                float c  = fg * cst[r] + ig * gg;
                cst[r] = c;
                float h = og * tanhf(c);
                if (t < Lr[r]) sum[r] += h;
                f16 hh = (f16)h;
                f16 hl = (f16)((h - (float)hh) * 2048.0f);
                unsigned off = (unsigned)(wave * 16 + quad * 4 + r) * 640u + pc + l15;
                // write-through (agent scope) so the release-add publishes them cross-XCD
                __hip_atomic_store((unsigned short*)(hnxt + off),
                                   __builtin_bit_cast(unsigned short, hh),
                                   __ATOMIC_RELAXED, __HIP_MEMORY_SCOPE_AGENT);
                __hip_atomic_store((unsigned short*)(hnxt + 64 * 640 + off),
                                   __builtin_bit_cast(unsigned short, hl),
                                   __ATOMIC_RELAXED, __HIP_MEMORY_SCOPE_AGENT);
            }
        }
        __syncthreads();   // drains all waves' stores (vmcnt(0) before barrier)
        if (tid == 0)
            __hip_atomic_fetch_add(myctr, 1u, __ATOMIC_RELEASE, __HIP_MEMORY_SCOPE_AGENT);
    }

    if (l15 < 8) {
#pragma unroll
        for (int r = 0; r < 4; ++r)
            out[(wave * 16 + quad * 4 + r) * 1200 + dir * 600 + pc + l15] =
                sum[r] * (1.0f / 512.0f);
    }
}

// ---------------- launcher ----------------
extern "C" void kernel_launch(void* const* d_in, const int* in_sizes, int n_in,
                              void* d_out, int out_size, void* d_ws, size_t ws_size,
                              hipStream_t stream) {
    const float* x   = (const float*)d_in[0];
    const int*   len = (const int*)  d_in[1];
    const float* Wf  = (const float*)d_in[3];
    const float* Uf  = (const float*)d_in[4];
    const float* bfv = (const float*)d_in[5];
    const float* Wb  = (const float*)d_in[6];
    const float* Ub  = (const float*)d_in[7];
    const float* bbv = (const float*)d_in[8];
    float* outp = (float*)d_out;

    char* w = (char*)d_ws;
    f16*      x16hp = (f16*)w;                         // 20,971,520 B
    f16*      x16lp = (f16*)(w + 20971520);            // 20,971,520 B
    f16*      bpkp  = (f16*)(w + 41943040);            // 18,432,000 B
    f16*      hbufp = (f16*)(w + 60375040);            //  1,310,720 B (planes)
    unsigned* ctrp  = (unsigned*)(w + 61741056);       //        256 B
    int*      maxtp = (int*)(w + 61741312);

    hipLaunchKernelGGL(lstm_prep, dim3(1024), dim3(256), 0, stream,
                       x, Wf, Uf, Wb, Ub, len,
                       x16hp, x16lp, bpkp, (unsigned*)hbufp, ctrp, maxtp, outp);

    // Plain launch: no grid.sync() is used, only co-residency. 150 blocks of
    // 256 threads (32 KB LDS, <=1 block/CU by VGPRs) on 256 CUs are all
    // dispatched immediately; the flag protocol is dispatch-order-independent.
    hipLaunchKernelGGL(lstm_main, dim3(GRID_MAIN), dim3(256), 0, stream,
                       x16hp, x16lp, bpkp, hbufp, ctrp, maxtp, len, bfv, bbv, outp);
}